// Round 1
// baseline (62972.156 us; speedup 1.0000x reference)
//
#include <hip/hip_runtime.h>
#include <math.h>

#define T_STEPS 4096
#define HDIM    2048
#define KDIM    2048
#define NG      8192   // 4*H

// ---------------- init: zero barrier counters ----------------
__global__ void init_ws(unsigned int* __restrict__ ctr) {
    ctr[threadIdx.x] = 0u;   // 512 uints cover grp counters + global counter
}

// ---------------- Phase 1: Y = X @ Wi + bias (fp32 tiled GEMM) ----------------
// grid (NG/64, T/64), 256 threads. 64x64 tile, BK=16, 4x4 per thread.
__global__ __launch_bounds__(256) void gemm_xwi(
    const float* __restrict__ X,     // [T][K]
    const float* __restrict__ Wi,    // [K][NG]
    const float* __restrict__ bias,  // [NG]
    float* __restrict__ Y)           // [T][NG]
{
    __shared__ float As[16][65];                 // transposed A tile, +1 pad
    __shared__ __align__(16) float Bs[16][64];
    const int tid = threadIdx.x;
    const int m0 = blockIdx.y * 64;
    const int n0 = blockIdx.x * 64;
    const int tx4 = (tid & 15) * 4;
    const int ty4 = (tid >> 4) * 4;
    const int am = tid >> 2, ak = (tid & 3) * 4; // A load: x[m0+am][kt+ak..+3]
    const int bk = tid >> 4, bn = (tid & 15) * 4;// B load: Wi[kt+bk][n0+bn..+3]

    float acc[4][4];
#pragma unroll
    for (int i = 0; i < 4; ++i)
#pragma unroll
        for (int j = 0; j < 4; ++j) acc[i][j] = 0.f;

    for (int kt = 0; kt < KDIM; kt += 16) {
        float4 av = *reinterpret_cast<const float4*>(&X[(size_t)(m0 + am) * KDIM + kt + ak]);
        float4 bv = *reinterpret_cast<const float4*>(&Wi[(size_t)(kt + bk) * NG + n0 + bn]);
        __syncthreads();
        As[ak + 0][am] = av.x; As[ak + 1][am] = av.y;
        As[ak + 2][am] = av.z; As[ak + 3][am] = av.w;
        *reinterpret_cast<float4*>(&Bs[bk][bn]) = bv;
        __syncthreads();
#pragma unroll
        for (int k = 0; k < 16; ++k) {
            float a0 = As[k][ty4 + 0], a1 = As[k][ty4 + 1];
            float a2 = As[k][ty4 + 2], a3 = As[k][ty4 + 3];
            float4 b4 = *reinterpret_cast<const float4*>(&Bs[k][tx4]);
            acc[0][0] = fmaf(a0, b4.x, acc[0][0]); acc[0][1] = fmaf(a0, b4.y, acc[0][1]);
            acc[0][2] = fmaf(a0, b4.z, acc[0][2]); acc[0][3] = fmaf(a0, b4.w, acc[0][3]);
            acc[1][0] = fmaf(a1, b4.x, acc[1][0]); acc[1][1] = fmaf(a1, b4.y, acc[1][1]);
            acc[1][2] = fmaf(a1, b4.z, acc[1][2]); acc[1][3] = fmaf(a1, b4.w, acc[1][3]);
            acc[2][0] = fmaf(a2, b4.x, acc[2][0]); acc[2][1] = fmaf(a2, b4.y, acc[2][1]);
            acc[2][2] = fmaf(a2, b4.z, acc[2][2]); acc[2][3] = fmaf(a2, b4.w, acc[2][3]);
            acc[3][0] = fmaf(a3, b4.x, acc[3][0]); acc[3][1] = fmaf(a3, b4.y, acc[3][1]);
            acc[3][2] = fmaf(a3, b4.z, acc[3][2]); acc[3][3] = fmaf(a3, b4.w, acc[3][3]);
        }
    }
    float4 bb = *reinterpret_cast<const float4*>(&bias[n0 + tx4]);
#pragma unroll
    for (int i = 0; i < 4; ++i) {
        float4 o;
        o.x = acc[i][0] + bb.x; o.y = acc[i][1] + bb.y;
        o.z = acc[i][2] + bb.z; o.w = acc[i][3] + bb.w;
        *reinterpret_cast<float4*>(&Y[(size_t)(m0 + ty4 + i) * NG + n0 + tx4]) = o;
    }
}

// ---------------- Phase 2: persistent recurrent kernel ----------------
// 256 blocks x 512 threads, cooperative (all co-resident, 1 block/CU).
// Block b owns h-indices [8b, 8b+8) -> 32 gate columns {2048*g + 8b + d}.
// Wave w (of 8): gate gg=w>>1, h-subgroup hg=w&1 -> 4 columns nbase..nbase+3.
// Lane l holds Wh[k][nbase..nbase+3] for k in {4l+256j+m : j<8, m<4} = 128 VGPRs.
__global__ __launch_bounds__(512, 2) void lstm_persistent(
    const float* __restrict__ Y,    // [T][NG] precomputed x@Wi + b
    const float* __restrict__ h0,
    const float* __restrict__ c0,
    const float* __restrict__ Wh,   // [K][NG]
    float* __restrict__ hbuf,       // [2][HDIM] ping-pong
    unsigned int* __restrict__ ctr, // [512]: grp g at ctr[g*32], global at ctr[256]
    float* __restrict__ out)        // [HDIM c_f][HDIM h_f][T*HDIM ys]
{
    const int b    = blockIdx.x;      // 0..255
    const int tid  = threadIdx.x;     // 0..511
    const int lane = tid & 63;
    const int w    = tid >> 6;        // 0..7
    const int gg   = w >> 1;          // gate 0..3 (i,f,g,o)
    const int hg   = w & 1;
    const int nbase = (gg << 11) + (b << 3) + (hg << 2);

    __shared__ float4 hlds4[HDIM / 4];
    float* hlds = reinterpret_cast<float*>(hlds4);
    __shared__ float gates[32];       // [gg*8 + hg*4 + d]
    __shared__ float c_s[8];
    __shared__ float hlast[8];

    // Load weight slice into registers (once).
    float4 wreg[32];
#pragma unroll
    for (int j = 0; j < 8; ++j)
#pragma unroll
        for (int m = 0; m < 4; ++m) {
            const size_t k = (size_t)(4 * lane + 256 * j + m);
            wreg[j * 4 + m] = *reinterpret_cast<const float4*>(&Wh[k * NG + nbase]);
        }

    if (tid < 8) c_s[tid] = c0[b * 8 + tid];
    __syncthreads();

    unsigned int* grpCnt = ctr;        // group g at ctr[g*32]
    unsigned int* gCnt   = ctr + 256;

    for (int t = 0; t < T_STEPS; ++t) {
        // ---- stage h into LDS (agent-scope loads: bypass stale L1) ----
        const float* rb = (t == 0) ? h0 : (hbuf + (size_t)((t - 1) & 1) * HDIM);
        float4 hv;
        hv.x = __hip_atomic_load(rb + 4 * tid + 0, __ATOMIC_RELAXED, __HIP_MEMORY_SCOPE_AGENT);
        hv.y = __hip_atomic_load(rb + 4 * tid + 1, __ATOMIC_RELAXED, __HIP_MEMORY_SCOPE_AGENT);
        hv.z = __hip_atomic_load(rb + 4 * tid + 2, __ATOMIC_RELAXED, __HIP_MEMORY_SCOPE_AGENT);
        hv.w = __hip_atomic_load(rb + 4 * tid + 3, __ATOMIC_RELAXED, __HIP_MEMORY_SCOPE_AGENT);
        hlds4[tid] = hv;
        // prefetch precomputed input-GEMM contribution for this wave's 4 columns
        float yv = 0.f;
        if (lane < 4) yv = Y[(size_t)t * NG + nbase + lane];
        __syncthreads();

        // ---- 128 FMAs: acc[d] = sum_k h[k] * Wh[k][nbase+d] (thread's k-slice) ----
        float4 acc; acc.x = acc.y = acc.z = acc.w = 0.f;
#pragma unroll
        for (int j = 0; j < 8; ++j) {
            float4 h4 = hlds4[lane + 64 * j];   // h[4*lane + 256*j .. +3], conflict-free
            float4 w0 = wreg[4 * j + 0], w1 = wreg[4 * j + 1];
            float4 w2 = wreg[4 * j + 2], w3 = wreg[4 * j + 3];
            acc.x = fmaf(h4.x, w0.x, acc.x); acc.x = fmaf(h4.y, w1.x, acc.x);
            acc.x = fmaf(h4.z, w2.x, acc.x); acc.x = fmaf(h4.w, w3.x, acc.x);
            acc.y = fmaf(h4.x, w0.y, acc.y); acc.y = fmaf(h4.y, w1.y, acc.y);
            acc.y = fmaf(h4.z, w2.y, acc.y); acc.y = fmaf(h4.w, w3.y, acc.y);
            acc.z = fmaf(h4.x, w0.z, acc.z); acc.z = fmaf(h4.y, w1.z, acc.z);
            acc.z = fmaf(h4.z, w2.z, acc.z); acc.z = fmaf(h4.w, w3.z, acc.z);
            acc.w = fmaf(h4.x, w0.w, acc.w); acc.w = fmaf(h4.y, w1.w, acc.w);
            acc.w = fmaf(h4.z, w2.w, acc.w); acc.w = fmaf(h4.w, w3.w, acc.w);
        }
        // ---- butterfly reduce each component across 64 lanes ----
#pragma unroll
        for (int off = 32; off >= 1; off >>= 1) {
            acc.x += __shfl_xor(acc.x, off);
            acc.y += __shfl_xor(acc.y, off);
            acc.z += __shfl_xor(acc.z, off);
            acc.w += __shfl_xor(acc.w, off);
        }
        if (lane < 4) {
            float v = (lane == 0) ? acc.x : (lane == 1) ? acc.y : (lane == 2) ? acc.z : acc.w;
            gates[gg * 8 + hg * 4 + lane] = v + yv;
        }
        __syncthreads();

        // ---- epilogue: 8 h-outputs for this block ----
        if (tid < 8) {
            float iv = gates[0 * 8 + tid];
            float fv = gates[1 * 8 + tid];
            float gv = gates[2 * 8 + tid];
            float ov = gates[3 * 8 + tid];
            float si = 1.f / (1.f + expf(-iv));
            float sf = 1.f / (1.f + expf(-fv));
            float tg = tanhf(gv);
            float so = 1.f / (1.f + expf(-ov));
            float cn = sf * c_s[tid] + si * tg;
            float hn = so * tanhf(cn);
            c_s[tid] = cn;
            hlast[tid] = hn;
            out[2 * HDIM + (size_t)t * HDIM + b * 8 + tid] = hn;   // ys
            __hip_atomic_store(hbuf + (size_t)(t & 1) * HDIM + b * 8 + tid, hn,
                               __ATOMIC_RELEASE, __HIP_MEMORY_SCOPE_AGENT);
        }
        __syncthreads();

        // ---- device-wide barrier (hierarchical, monotonic counters) ----
        if (tid == 0) {
            __threadfence();
            const int grp = b >> 5;                           // 8 groups of 32 blocks
            unsigned old = atomicAdd(&grpCnt[grp * 32], 1u);  // device-scope by default
            if (old == (unsigned)(32 * (t + 1) - 1))
                atomicAdd(gCnt, 1u);
            const unsigned target = 8u * (unsigned)(t + 1);
            while (__hip_atomic_load(gCnt, __ATOMIC_ACQUIRE, __HIP_MEMORY_SCOPE_AGENT) < target)
                __builtin_amdgcn_s_sleep(1);
        }
        __syncthreads();
    }

    if (tid < 8) {
        out[b * 8 + tid]        = c_s[tid];   // c_f
        out[HDIM + b * 8 + tid] = hlast[tid]; // h_f
    }
}

// ---------------- launch ----------------
extern "C" void kernel_launch(void* const* d_in, const int* in_sizes, int n_in,
                              void* d_out, int out_size, void* d_ws, size_t ws_size,
                              hipStream_t stream) {
    const float* x   = (const float*)d_in[0];
    const float* c0  = (const float*)d_in[1];
    const float* h0  = (const float*)d_in[2];
    const float* Wi  = (const float*)d_in[3];
    const float* Wh  = (const float*)d_in[4];
    const float* bia = (const float*)d_in[5];
    float* out = (float*)d_out;

    // workspace layout
    float* Y = (float*)d_ws;                                    // 4096*8192*4 = 128 MiB
    char* p = (char*)d_ws + (size_t)T_STEPS * NG * sizeof(float);
    float* hbuf = (float*)p;                                    // 2*2048 floats
    unsigned int* ctr = (unsigned int*)(p + 2 * HDIM * sizeof(float)); // 512 uints

    hipLaunchKernelGGL(init_ws, dim3(1), dim3(512), 0, stream, ctr);
    hipLaunchKernelGGL(gemm_xwi, dim3(NG / 64, T_STEPS / 64), dim3(256), 0, stream,
                       x, Wi, bia, Y);

    void* args[] = { (void*)&Y, (void*)&h0, (void*)&c0, (void*)&Wh,
                     (void*)&hbuf, (void*)&ctr, (void*)&out };
    hipLaunchCooperativeKernel((const void*)lstm_persistent, dim3(256), dim3(512),
                               args, 0, stream);
}

// Round 2
// 20417.728 us; speedup vs baseline: 3.0842x; 3.0842x over previous
//
#include <hip/hip_runtime.h>
#include <math.h>

#define T_STEPS 4096
#define HDIM    2048
#define KDIM    2048
#define NG      8192   // 4*H

// ---------------- init: seed h ping-pong buffer with tags ----------------
// hbuf layout: uint64 [2][HDIM]; word = (tag << 32) | float_bits.
// Step-t readers read slot (t+1)&1 expecting tag t; step-t writers store
// tag t+1 into slot t&1. Seed: slot1 = {h0, tag 0}; slot0 = invalid tag.
__global__ void init_hbuf(const float* __restrict__ h0,
                          unsigned long long* __restrict__ hbuf) {
    int g = blockIdx.x * blockDim.x + threadIdx.x;   // 0..4095
    if (g < HDIM) {
        union { float f; unsigned u; } cv; cv.f = h0[g];
        hbuf[HDIM + g] = (unsigned long long)cv.u;   // tag 0 in high bits
    } else {
        hbuf[g - HDIM] = 0xFFFFFFFF00000000ull;      // never-matching tag
    }
}

// ---------------- Phase 1: Y = X @ Wi + bias (fp32 tiled GEMM) ----------------
__global__ __launch_bounds__(256) void gemm_xwi(
    const float* __restrict__ X,     // [T][K]
    const float* __restrict__ Wi,    // [K][NG]
    const float* __restrict__ bias,  // [NG]
    float* __restrict__ Y)           // [T][NG]
{
    __shared__ float As[16][65];
    __shared__ __align__(16) float Bs[16][64];
    const int tid = threadIdx.x;
    const int m0 = blockIdx.y * 64;
    const int n0 = blockIdx.x * 64;
    const int tx4 = (tid & 15) * 4;
    const int ty4 = (tid >> 4) * 4;
    const int am = tid >> 2, ak = (tid & 3) * 4;
    const int bk = tid >> 4, bn = (tid & 15) * 4;

    float acc[4][4];
#pragma unroll
    for (int i = 0; i < 4; ++i)
#pragma unroll
        for (int j = 0; j < 4; ++j) acc[i][j] = 0.f;

    for (int kt = 0; kt < KDIM; kt += 16) {
        float4 av = *reinterpret_cast<const float4*>(&X[(size_t)(m0 + am) * KDIM + kt + ak]);
        float4 bv = *reinterpret_cast<const float4*>(&Wi[(size_t)(kt + bk) * NG + n0 + bn]);
        __syncthreads();
        As[ak + 0][am] = av.x; As[ak + 1][am] = av.y;
        As[ak + 2][am] = av.z; As[ak + 3][am] = av.w;
        *reinterpret_cast<float4*>(&Bs[bk][bn]) = bv;
        __syncthreads();
#pragma unroll
        for (int k = 0; k < 16; ++k) {
            float a0 = As[k][ty4 + 0], a1 = As[k][ty4 + 1];
            float a2 = As[k][ty4 + 2], a3 = As[k][ty4 + 3];
            float4 b4 = *reinterpret_cast<const float4*>(&Bs[k][tx4]);
            acc[0][0] = fmaf(a0, b4.x, acc[0][0]); acc[0][1] = fmaf(a0, b4.y, acc[0][1]);
            acc[0][2] = fmaf(a0, b4.z, acc[0][2]); acc[0][3] = fmaf(a0, b4.w, acc[0][3]);
            acc[1][0] = fmaf(a1, b4.x, acc[1][0]); acc[1][1] = fmaf(a1, b4.y, acc[1][1]);
            acc[1][2] = fmaf(a1, b4.z, acc[1][2]); acc[1][3] = fmaf(a1, b4.w, acc[1][3]);
            acc[2][0] = fmaf(a2, b4.x, acc[2][0]); acc[2][1] = fmaf(a2, b4.y, acc[2][1]);
            acc[2][2] = fmaf(a2, b4.z, acc[2][2]); acc[2][3] = fmaf(a2, b4.w, acc[2][3]);
            acc[3][0] = fmaf(a3, b4.x, acc[3][0]); acc[3][1] = fmaf(a3, b4.y, acc[3][1]);
            acc[3][2] = fmaf(a3, b4.z, acc[3][2]); acc[3][3] = fmaf(a3, b4.w, acc[3][3]);
        }
    }
    float4 bb = *reinterpret_cast<const float4*>(&bias[n0 + tx4]);
#pragma unroll
    for (int i = 0; i < 4; ++i) {
        float4 o;
        o.x = acc[i][0] + bb.x; o.y = acc[i][1] + bb.y;
        o.z = acc[i][2] + bb.z; o.w = acc[i][3] + bb.w;
        *reinterpret_cast<float4*>(&Y[(size_t)(m0 + ty4 + i) * NG + n0 + tx4]) = o;
    }
}

// ---------------- fast activations (8 threads/block only) ----------------
__device__ __forceinline__ float fsigm(float x) {
    return 1.f / (1.f + __expf(-x));   // saturates correctly at +/-inf
}
__device__ __forceinline__ float ftanh(float x) {
    float ax = fabsf(x);
    float e  = __expf(2.f * ax);
    float t  = (e - 1.f) / (e + 1.f);
    t = (ax > 15.f) ? 1.f : t;
    return copysignf(t, x);
}

// ---------------- Phase 2: persistent recurrent kernel ----------------
// 256 blocks x 512 threads, cooperative, 1 block/CU.
// Block b owns h-indices [8b,8b+8) -> 32 gate columns {2048*g + 8b + d}.
// Wave w: gate gg=w>>1, half hg=w&1 -> 4 columns nbase..nbase+3.
// Lane l: k in {4l+256j+m : j<8,m<4} -> 32 float4 of Wh, forced into VGPRs.
__global__ __launch_bounds__(512, 2) void lstm_persistent(
    const float* __restrict__ Y,             // [T][NG]
    const float* __restrict__ c0,
    const float* __restrict__ Wh,            // [K][NG]
    unsigned long long* __restrict__ hbuf,   // [2][HDIM] tagged ping-pong
    float* __restrict__ out)                 // [c_f][h_f][ys]
{
    const int b    = blockIdx.x;
    const int tid  = threadIdx.x;
    const int lane = tid & 63;
    const int w    = tid >> 6;
    const int gg   = w >> 1;
    const int hg   = w & 1;
    const int nbase = (gg << 11) + (b << 3) + (hg << 2);

    __shared__ float4 hlds4[HDIM / 4];   // 8 KiB
    __shared__ float gates[32];
    __shared__ float c_s[8];
    __shared__ float hlast[8];

    // ---- load weight slice once, force VGPR residency ----
    float4 wreg[32];
#pragma unroll
    for (int j = 0; j < 8; ++j)
#pragma unroll
        for (int m = 0; m < 4; ++m) {
            const size_t k = (size_t)(4 * lane + 256 * j + m);
            wreg[j * 4 + m] = *reinterpret_cast<const float4*>(&Wh[k * NG + nbase]);
        }
#pragma unroll
    for (int i = 0; i < 32; ++i) {
        asm volatile("" : "+v"(wreg[i].x), "+v"(wreg[i].y),
                          "+v"(wreg[i].z), "+v"(wreg[i].w));
    }

    if (tid < 8) c_s[tid] = c0[b * 8 + tid];
    __syncthreads();

    for (int t = 0; t < T_STEPS; ++t) {
        // ---- issue Y prefetch early (hidden under the poll) ----
        float yv = 0.f;
        if (lane < 4) yv = Y[(size_t)t * NG + nbase + lane];

        // ---- gather h: poll tagged words (relaxed agent atomics, no fences) ----
        const unsigned long long* hs = hbuf + (size_t)((t + 1) & 1) * HDIM + 4 * tid;
        const unsigned long long tg = (unsigned long long)(unsigned)t;
        unsigned long long p0, p1, p2, p3;
        for (;;) {
            p0 = __hip_atomic_load(hs + 0, __ATOMIC_RELAXED, __HIP_MEMORY_SCOPE_AGENT);
            p1 = __hip_atomic_load(hs + 1, __ATOMIC_RELAXED, __HIP_MEMORY_SCOPE_AGENT);
            p2 = __hip_atomic_load(hs + 2, __ATOMIC_RELAXED, __HIP_MEMORY_SCOPE_AGENT);
            p3 = __hip_atomic_load(hs + 3, __ATOMIC_RELAXED, __HIP_MEMORY_SCOPE_AGENT);
            if (((p0 >> 32) == tg) & ((p1 >> 32) == tg) &
                ((p2 >> 32) == tg) & ((p3 >> 32) == tg)) break;
            __builtin_amdgcn_s_sleep(2);
        }
        union { unsigned u; float f; } c0u, c1u, c2u, c3u;
        c0u.u = (unsigned)p0; c1u.u = (unsigned)p1;
        c2u.u = (unsigned)p2; c3u.u = (unsigned)p3;
        float4 hv; hv.x = c0u.f; hv.y = c1u.f; hv.z = c2u.f; hv.w = c3u.f;
        hlds4[tid] = hv;
        __syncthreads();

        // ---- 128 FMAs on register-resident weights ----
        float4 acc; acc.x = acc.y = acc.z = acc.w = 0.f;
#pragma unroll
        for (int j = 0; j < 8; ++j) {
            float4 h4 = hlds4[lane + 64 * j];
            float4 w0 = wreg[4 * j + 0], w1 = wreg[4 * j + 1];
            float4 w2 = wreg[4 * j + 2], w3 = wreg[4 * j + 3];
            acc.x = fmaf(h4.x, w0.x, acc.x); acc.x = fmaf(h4.y, w1.x, acc.x);
            acc.x = fmaf(h4.z, w2.x, acc.x); acc.x = fmaf(h4.w, w3.x, acc.x);
            acc.y = fmaf(h4.x, w0.y, acc.y); acc.y = fmaf(h4.y, w1.y, acc.y);
            acc.y = fmaf(h4.z, w2.y, acc.y); acc.y = fmaf(h4.w, w3.y, acc.y);
            acc.z = fmaf(h4.x, w0.z, acc.z); acc.z = fmaf(h4.y, w1.z, acc.z);
            acc.z = fmaf(h4.z, w2.z, acc.z); acc.z = fmaf(h4.w, w3.z, acc.z);
            acc.w = fmaf(h4.x, w0.w, acc.w); acc.w = fmaf(h4.y, w1.w, acc.w);
            acc.w = fmaf(h4.z, w2.w, acc.w); acc.w = fmaf(h4.w, w3.w, acc.w);
        }
#pragma unroll
        for (int off = 32; off >= 1; off >>= 1) {
            acc.x += __shfl_xor(acc.x, off);
            acc.y += __shfl_xor(acc.y, off);
            acc.z += __shfl_xor(acc.z, off);
            acc.w += __shfl_xor(acc.w, off);
        }
        if (lane < 4) {
            float v = (lane == 0) ? acc.x : (lane == 1) ? acc.y
                    : (lane == 2) ? acc.z : acc.w;
            gates[gg * 8 + hg * 4 + lane] = v + yv;
        }
        __syncthreads();

        // ---- epilogue: 8 h outputs; publish via single tagged relaxed store ----
        if (tid < 8) {
            float iv = gates[0 * 8 + tid];
            float fv = gates[1 * 8 + tid];
            float gv = gates[2 * 8 + tid];
            float ov = gates[3 * 8 + tid];
            float cn = fsigm(fv) * c_s[tid] + fsigm(iv) * ftanh(gv);
            float hn = fsigm(ov) * ftanh(cn);
            c_s[tid] = cn;
            hlast[tid] = hn;
            out[2 * HDIM + (size_t)t * HDIM + b * 8 + tid] = hn;   // ys
            union { float f; unsigned u; } cv; cv.f = hn;
            unsigned long long pk =
                ((unsigned long long)(unsigned)(t + 1) << 32) | (unsigned long long)cv.u;
            __hip_atomic_store(hbuf + (size_t)(t & 1) * HDIM + b * 8 + tid, pk,
                               __ATOMIC_RELAXED, __HIP_MEMORY_SCOPE_AGENT);
        }
        // NOTE: no device-wide barrier — the tag dataflow IS the barrier.
        // (2-slot ping-pong is sufficient: producing h(t+1) requires having
        //  consumed all of h(t), so no writer can lap a reader.)
    }

    if (tid < 8) {
        out[b * 8 + tid]        = c_s[tid];   // c_f
        out[HDIM + b * 8 + tid] = hlast[tid]; // h_f
    }
}

// ---------------- launch ----------------
extern "C" void kernel_launch(void* const* d_in, const int* in_sizes, int n_in,
                              void* d_out, int out_size, void* d_ws, size_t ws_size,
                              hipStream_t stream) {
    const float* x   = (const float*)d_in[0];
    const float* c0  = (const float*)d_in[1];
    const float* h0  = (const float*)d_in[2];
    const float* Wi  = (const float*)d_in[3];
    const float* Wh  = (const float*)d_in[4];
    const float* bia = (const float*)d_in[5];
    float* out = (float*)d_out;

    float* Y = (float*)d_ws;                                   // 128 MiB
    unsigned long long* hbuf =
        (unsigned long long*)((char*)d_ws + (size_t)T_STEPS * NG * sizeof(float));

    hipLaunchKernelGGL(init_hbuf, dim3(8), dim3(512), 0, stream, h0, hbuf);
    hipLaunchKernelGGL(gemm_xwi, dim3(NG / 64, T_STEPS / 64), dim3(256), 0, stream,
                       x, Wi, bia, Y);

    void* args[] = { (void*)&Y, (void*)&c0, (void*)&Wh, (void*)&hbuf, (void*)&out };
    hipLaunchCooperativeKernel((const void*)lstm_persistent, dim3(256), dim3(512),
                               args, 0, stream);
}

// Round 3
// 20336.859 us; speedup vs baseline: 3.0965x; 1.0040x over previous
//
#include <hip/hip_runtime.h>
#include <math.h>

#define T_STEPS 4096
#define HDIM    2048
#define KDIM    2048
#define NG      8192   // 4*H

// ---------------- init: seed h ping-pong buffer with tags ----------------
// hbuf layout: uint64 [2][HDIM]; word = (tag << 32) | float_bits.
// Step-t readers read slot (t+1)&1 expecting tag t; step-t writers store
// tag t+1 into slot t&1. Seed: slot1 = {h0, tag 0}; slot0 = invalid tag.
__global__ void init_hbuf(const float* __restrict__ h0,
                          unsigned long long* __restrict__ hbuf) {
    int g = blockIdx.x * blockDim.x + threadIdx.x;   // 0..4095
    if (g < HDIM) {
        union { float f; unsigned u; } cv; cv.f = h0[g];
        hbuf[HDIM + g] = (unsigned long long)cv.u;   // tag 0 in high bits
    } else {
        hbuf[g - HDIM] = 0xFFFFFFFF00000000ull;      // never-matching tag
    }
}

// ---------------- Phase 1: Y = X @ Wi + bias (fp32 tiled GEMM) ----------------
__global__ __launch_bounds__(256) void gemm_xwi(
    const float* __restrict__ X,     // [T][K]
    const float* __restrict__ Wi,    // [K][NG]
    const float* __restrict__ bias,  // [NG]
    float* __restrict__ Y)           // [T][NG]
{
    __shared__ float As[16][65];
    __shared__ __align__(16) float Bs[16][64];
    const int tid = threadIdx.x;
    const int m0 = blockIdx.y * 64;
    const int n0 = blockIdx.x * 64;
    const int tx4 = (tid & 15) * 4;
    const int ty4 = (tid >> 4) * 4;
    const int am = tid >> 2, ak = (tid & 3) * 4;
    const int bk = tid >> 4, bn = (tid & 15) * 4;

    float acc[4][4];
#pragma unroll
    for (int i = 0; i < 4; ++i)
#pragma unroll
        for (int j = 0; j < 4; ++j) acc[i][j] = 0.f;

    for (int kt = 0; kt < KDIM; kt += 16) {
        float4 av = *reinterpret_cast<const float4*>(&X[(size_t)(m0 + am) * KDIM + kt + ak]);
        float4 bv = *reinterpret_cast<const float4*>(&Wi[(size_t)(kt + bk) * NG + n0 + bn]);
        __syncthreads();
        As[ak + 0][am] = av.x; As[ak + 1][am] = av.y;
        As[ak + 2][am] = av.z; As[ak + 3][am] = av.w;
        *reinterpret_cast<float4*>(&Bs[bk][bn]) = bv;
        __syncthreads();
#pragma unroll
        for (int k = 0; k < 16; ++k) {
            float a0 = As[k][ty4 + 0], a1 = As[k][ty4 + 1];
            float a2 = As[k][ty4 + 2], a3 = As[k][ty4 + 3];
            float4 b4 = *reinterpret_cast<const float4*>(&Bs[k][tx4]);
            acc[0][0] = fmaf(a0, b4.x, acc[0][0]); acc[0][1] = fmaf(a0, b4.y, acc[0][1]);
            acc[0][2] = fmaf(a0, b4.z, acc[0][2]); acc[0][3] = fmaf(a0, b4.w, acc[0][3]);
            acc[1][0] = fmaf(a1, b4.x, acc[1][0]); acc[1][1] = fmaf(a1, b4.y, acc[1][1]);
            acc[1][2] = fmaf(a1, b4.z, acc[1][2]); acc[1][3] = fmaf(a1, b4.w, acc[1][3]);
            acc[2][0] = fmaf(a2, b4.x, acc[2][0]); acc[2][1] = fmaf(a2, b4.y, acc[2][1]);
            acc[2][2] = fmaf(a2, b4.z, acc[2][2]); acc[2][3] = fmaf(a2, b4.w, acc[2][3]);
            acc[3][0] = fmaf(a3, b4.x, acc[3][0]); acc[3][1] = fmaf(a3, b4.y, acc[3][1]);
            acc[3][2] = fmaf(a3, b4.z, acc[3][2]); acc[3][3] = fmaf(a3, b4.w, acc[3][3]);
        }
    }
    float4 bb = *reinterpret_cast<const float4*>(&bias[n0 + tx4]);
#pragma unroll
    for (int i = 0; i < 4; ++i) {
        float4 o;
        o.x = acc[i][0] + bb.x; o.y = acc[i][1] + bb.y;
        o.z = acc[i][2] + bb.z; o.w = acc[i][3] + bb.w;
        *reinterpret_cast<float4*>(&Y[(size_t)(m0 + ty4 + i) * NG + n0 + tx4]) = o;
    }
}

// ---------------- fast activations ----------------
__device__ __forceinline__ float fsigm(float x) {
    return 1.f / (1.f + __expf(-x));
}
__device__ __forceinline__ float ftanh(float x) {
    float ax = fabsf(x);
    float e  = __expf(2.f * ax);
    float t  = (e - 1.f) / (e + 1.f);
    t = (ax > 15.f) ? 1.f : t;
    return copysignf(t, x);
}

// ---------------- Phase 2: persistent recurrent kernel ----------------
// 256 blocks x 512 threads, cooperative, 1 block/CU.
// h-exchange words use SYSTEM scope -> sc0+sc1 -> bypass L1 AND per-XCD L2,
// served by the (coherent, memory-side) Infinity Cache. Round 2 showed
// AGENT-scope polls get served stale from local L2 and only progress on
// eviction (~4.5us/step); SYSTEM scope makes detection a real MALL trip.
__global__ __launch_bounds__(512, 2) void lstm_persistent(
    const float* __restrict__ Y,             // [T][NG]
    const float* __restrict__ c0,
    const float* __restrict__ Wh,            // [K][NG]
    unsigned long long* __restrict__ hbuf,   // [2][HDIM] tagged ping-pong
    float* __restrict__ out)                 // [c_f][h_f][ys]
{
    const int b    = blockIdx.x;
    const int tid  = threadIdx.x;
    const int lane = tid & 63;
    const int w    = tid >> 6;
    const int gg   = w >> 1;
    const int hg   = w & 1;
    const int nbase = (gg << 11) + (b << 3) + (hg << 2);

    __shared__ float4 hlds4[HDIM / 4];   // 8 KiB
    __shared__ float gates[32];
    __shared__ float c_s[8];
    __shared__ float hlast[8];

    // ---- load weight slice once, force register residency ----
    float4 wreg[32];
#pragma unroll
    for (int j = 0; j < 8; ++j)
#pragma unroll
        for (int m = 0; m < 4; ++m) {
            const size_t k = (size_t)(4 * lane + 256 * j + m);
            wreg[j * 4 + m] = *reinterpret_cast<const float4*>(&Wh[k * NG + nbase]);
        }
#pragma unroll
    for (int i = 0; i < 32; ++i) {
        asm volatile("" : "+v"(wreg[i].x), "+v"(wreg[i].y),
                          "+v"(wreg[i].z), "+v"(wreg[i].w));
    }

    if (tid < 8) c_s[tid] = c0[b * 8 + tid];
    __syncthreads();

    for (int t = 0; t < T_STEPS; ++t) {
        // ---- issue Y prefetch early (hidden under the poll) ----
        float yv = 0.f;
        if (lane < 4) yv = Y[(size_t)t * NG + nbase + lane];

        // ---- gather h: poll tagged words (SYSTEM scope = MALL-coherent) ----
        const unsigned long long* hs = hbuf + (size_t)((t + 1) & 1) * HDIM + 4 * tid;
        const unsigned long long tg = (unsigned long long)(unsigned)t;
        unsigned long long p0, p1, p2, p3;
        for (;;) {
            p0 = __hip_atomic_load(hs + 0, __ATOMIC_RELAXED, __HIP_MEMORY_SCOPE_SYSTEM);
            p1 = __hip_atomic_load(hs + 1, __ATOMIC_RELAXED, __HIP_MEMORY_SCOPE_SYSTEM);
            p2 = __hip_atomic_load(hs + 2, __ATOMIC_RELAXED, __HIP_MEMORY_SCOPE_SYSTEM);
            p3 = __hip_atomic_load(hs + 3, __ATOMIC_RELAXED, __HIP_MEMORY_SCOPE_SYSTEM);
            if (((p0 >> 32) == tg) & ((p1 >> 32) == tg) &
                ((p2 >> 32) == tg) & ((p3 >> 32) == tg)) break;
            __builtin_amdgcn_s_sleep(1);
        }
        union { unsigned u; float f; } c0u, c1u, c2u, c3u;
        c0u.u = (unsigned)p0; c1u.u = (unsigned)p1;
        c2u.u = (unsigned)p2; c3u.u = (unsigned)p3;
        float4 hv; hv.x = c0u.f; hv.y = c1u.f; hv.z = c2u.f; hv.w = c3u.f;
        hlds4[tid] = hv;
        __syncthreads();

        // ---- 128 FMAs on register-resident weights ----
        float4 acc; acc.x = acc.y = acc.z = acc.w = 0.f;
#pragma unroll
        for (int j = 0; j < 8; ++j) {
            float4 h4 = hlds4[lane + 64 * j];
            float4 w0 = wreg[4 * j + 0], w1 = wreg[4 * j + 1];
            float4 w2 = wreg[4 * j + 2], w3 = wreg[4 * j + 3];
            acc.x = fmaf(h4.x, w0.x, acc.x); acc.x = fmaf(h4.y, w1.x, acc.x);
            acc.x = fmaf(h4.z, w2.x, acc.x); acc.x = fmaf(h4.w, w3.x, acc.x);
            acc.y = fmaf(h4.x, w0.y, acc.y); acc.y = fmaf(h4.y, w1.y, acc.y);
            acc.y = fmaf(h4.z, w2.y, acc.y); acc.y = fmaf(h4.w, w3.y, acc.y);
            acc.z = fmaf(h4.x, w0.z, acc.z); acc.z = fmaf(h4.y, w1.z, acc.z);
            acc.z = fmaf(h4.z, w2.z, acc.z); acc.z = fmaf(h4.w, w3.z, acc.z);
            acc.w = fmaf(h4.x, w0.w, acc.w); acc.w = fmaf(h4.y, w1.w, acc.w);
            acc.w = fmaf(h4.z, w2.w, acc.w); acc.w = fmaf(h4.w, w3.w, acc.w);
        }
#pragma unroll
        for (int off = 32; off >= 1; off >>= 1) {
            acc.x += __shfl_xor(acc.x, off);
            acc.y += __shfl_xor(acc.y, off);
            acc.z += __shfl_xor(acc.z, off);
            acc.w += __shfl_xor(acc.w, off);
        }
        if (lane < 4) {
            float v = (lane == 0) ? acc.x : (lane == 1) ? acc.y
                    : (lane == 2) ? acc.z : acc.w;
            gates[gg * 8 + hg * 4 + lane] = v + yv;
        }
        __syncthreads();

        // ---- epilogue: 8 h outputs; publish via tagged SYSTEM-scope store ----
        if (tid < 8) {
            float iv = gates[0 * 8 + tid];
            float fv = gates[1 * 8 + tid];
            float gv = gates[2 * 8 + tid];
            float ov = gates[3 * 8 + tid];
            float cn = fsigm(fv) * c_s[tid] + fsigm(iv) * ftanh(gv);
            float hn = fsigm(ov) * ftanh(cn);
            c_s[tid] = cn;
            hlast[tid] = hn;
            // ys: non-temporal (never re-read; keep L2 clean for Y/Wh streams)
            __builtin_nontemporal_store(hn, &out[2 * HDIM + (size_t)t * HDIM + b * 8 + tid]);
            union { float f; unsigned u; } cv; cv.f = hn;
            unsigned long long pk =
                ((unsigned long long)(unsigned)(t + 1) << 32) | (unsigned long long)cv.u;
            __hip_atomic_store(hbuf + (size_t)(t & 1) * HDIM + b * 8 + tid, pk,
                               __ATOMIC_RELAXED, __HIP_MEMORY_SCOPE_SYSTEM);
        }
        // No device-wide barrier: the tag dataflow IS the barrier.
        // 2-slot ping-pong sufficient (producer of h(t+1) consumed all h(t)).
    }

    if (tid < 8) {
        out[b * 8 + tid]        = c_s[tid];   // c_f
        out[HDIM + b * 8 + tid] = hlast[tid]; // h_f
    }
}

// ---------------- launch ----------------
extern "C" void kernel_launch(void* const* d_in, const int* in_sizes, int n_in,
                              void* d_out, int out_size, void* d_ws, size_t ws_size,
                              hipStream_t stream) {
    const float* x   = (const float*)d_in[0];
    const float* c0  = (const float*)d_in[1];
    const float* h0  = (const float*)d_in[2];
    const float* Wi  = (const float*)d_in[3];
    const float* Wh  = (const float*)d_in[4];
    const float* bia = (const float*)d_in[5];
    float* out = (float*)d_out;

    float* Y = (float*)d_ws;                                   // 128 MiB
    unsigned long long* hbuf =
        (unsigned long long*)((char*)d_ws + (size_t)T_STEPS * NG * sizeof(float));

    hipLaunchKernelGGL(init_hbuf, dim3(8), dim3(512), 0, stream, h0, hbuf);
    hipLaunchKernelGGL(gemm_xwi, dim3(NG / 64, T_STEPS / 64), dim3(256), 0, stream,
                       x, Wi, bia, Y);

    void* args[] = { (void*)&Y, (void*)&c0, (void*)&Wh, (void*)&hbuf, (void*)&out };
    hipLaunchCooperativeKernel((const void*)lstm_persistent, dim3(256), dim3(512),
                               args, 0, stream);
}